// Round 2
// baseline (1974.713 us; speedup 1.0000x reference)
//
#include <hip/hip_runtime.h>
#include <cstddef>
#include <cstdint>

#define DD 128

typedef __attribute__((ext_vector_type(8))) short short8;
typedef __attribute__((ext_vector_type(4))) float f32x4;

__device__ __forceinline__ unsigned short bf16_rne(float x) {
    union { float f; unsigned u; } a; a.f = x;
    unsigned u = a.u;
    u += 0x7FFFu + ((u >> 16) & 1u);
    return (unsigned short)(u >> 16);
}
__device__ __forceinline__ float bf16_f32(unsigned short h) {
    union { float f; unsigned u; } a; a.u = ((unsigned)h) << 16;
    return a.f;
}
__device__ __forceinline__ void split2(float x, unsigned short& h, unsigned short& l) {
    h = bf16_rne(x);
    l = bf16_rne(x - bf16_f32(h));
}

// ---------------------------------------------------------------------------
// Edge kernel, MFMA split-bf16 version.
//   per edge: m = ef@Wm + bm ; e = ef@We + be   (3-term hi/lo bf16 MFMA)
//   s = m*(q[src]-k[dst]) + e ; w = exp(s)      (softmax max-shift elided:
//                                                shift-invariant, |s| small)
//   unsafeAtomicAdd(den[dst], w) ; unsafeAtomicAdd(num[dst], v[src]*w)
//   plus fused passthrough copy of ef.
// Block = 512 thr (8 waves). Tile = 64 edges. Wave w owns channels [16w,16w+16),
// all 64 edges (mrep=4). Weights hi/lo in registers; A-tile hi/lo in
// XOR-swizzled LDS (T2); next-tile loads issued before compute (T14).
// MFMA 16x16x32_bf16: A[row=l&15][k=8*(l>>4)+j]; B[k=8*(l>>4)+j][col=l&15];
// C[row=4*(l>>4)+reg][col=l&15]  (m89-verified C layout).
// ---------------------------------------------------------------------------
__global__ __launch_bounds__(512, 2)
void edge_mfma(const float* __restrict__ ef,
               const float* __restrict__ Wm, const float* __restrict__ bm_,
               const float* __restrict__ We, const float* __restrict__ be_,
               const float* __restrict__ q, const float* __restrict__ kk_,
               const float* __restrict__ v,
               const int* __restrict__ src, const int* __restrict__ dst,
               float* __restrict__ num, float* __restrict__ den,
               float* __restrict__ ef_out, int E)
{
    __shared__ unsigned short AhL[64 * DD];   // hi bf16, swizzled [64][128]
    __shared__ unsigned short AlL[64 * DD];   // lo bf16
    __shared__ int sE[64], dE[64];

    const int t    = threadIdx.x;
    const int lane = t & 63;
    const int wid  = t >> 6;          // 0..7 -> channel group
    const int l15  = lane & 15;
    const int lhi  = lane >> 4;       // 0..3
    const int chan = wid * 16 + l15;  // this lane's output channel

    const float bmc = bm_[chan];
    const float bec = be_[chan];

    // ---- B fragments (weights), hi/lo split, registers, once per block ----
    short8 Bh[2][4], Bl[2][4];        // [matrix][kstep]
    #pragma unroll
    for (int mat = 0; mat < 2; ++mat) {
        const float* Wp = mat ? We : Wm;
        #pragma unroll
        for (int ks = 0; ks < 4; ++ks) {
            short8 h8, l8;
            #pragma unroll
            for (int j = 0; j < 8; ++j) {
                float w = Wp[(ks * 32 + lhi * 8 + j) * DD + chan];
                unsigned short h, l; split2(w, h, l);
                h8[j] = (short)h; l8[j] = (short)l;
            }
            Bh[mat][ks] = h8; Bl[mat][ks] = l8;
        }
    }

    const int ntiles = (E + 63) >> 6;
    const int per = (ntiles + gridDim.x - 1) / gridDim.x;
    const int t0 = blockIdx.x * per;
    const int t1 = min(ntiles, t0 + per);
    if (t0 >= t1) return;

    float4 bufA[4], bufB[4];
    int sA = 0, dA = 0, sB = 0, dB = 0;

    auto stage = [&](float4 (&RF)[4], int& RS, int& RD, int TILE) {
        const bool act = TILE < t1;
        const size_t base = (size_t)TILE * (64 * DD);
        #pragma unroll
        for (int p = 0; p < 4; ++p) {
            size_t idx = base + (size_t)(p * 512 + t) * 4;
            if (act && idx < (size_t)E * DD)
                RF[p] = *(const float4*)(ef + idx);
            else
                RF[p] = make_float4(0.f, 0.f, 0.f, 0.f);
        }
        if (t < 64) {
            int e64 = TILE * 64 + t;
            bool ok = act && (e64 < E);
            RS = ok ? src[e64] : 0;
            RD = ok ? dst[e64] : 0;
        }
    };

    auto ldswrite = [&](float4 (&RF)[4], int RS, int RD, int TILE) {
        const bool act = TILE < t1;
        if (t < 64) { sE[t] = RS; dE[t] = RD; }
        #pragma unroll
        for (int p = 0; p < 4; ++p) {
            int f  = (p * 512 + t) * 4;      // flat idx in 64x128 tile
            int eL = f >> 7;                 // edge row
            int byt = (eL * 256 + (f & 127) * 2) ^ ((eL & 7) << 4);  // T2 swizzle
            ushort4 hi4, lo4;
            split2(RF[p].x, hi4.x, lo4.x);
            split2(RF[p].y, hi4.y, lo4.y);
            split2(RF[p].z, hi4.z, lo4.z);
            split2(RF[p].w, hi4.w, lo4.w);
            *(ushort4*)((char*)AhL + byt) = hi4;
            *(ushort4*)((char*)AlL + byt) = lo4;
            size_t gidx = (size_t)TILE * (64 * DD) + f;
            if (act && gidx < (size_t)E * DD)
                *(float4*)(ef_out + gidx) = RF[p];  // fused passthrough
        }
    };

    auto compute = [&](int TILE) {
        f32x4 accM[4], accE[4];
        #pragma unroll
        for (int mr = 0; mr < 4; ++mr) {
            accM[mr] = (f32x4){0.f, 0.f, 0.f, 0.f};
            accE[mr] = (f32x4){0.f, 0.f, 0.f, 0.f};
        }
        #pragma unroll
        for (int ks = 0; ks < 4; ++ks) {
            short8 Ah[4], Al[4];
            #pragma unroll
            for (int mr = 0; mr < 4; ++mr) {
                int eL  = mr * 16 + l15;
                int byt = (eL * 256 + (ks * 32 + lhi * 8) * 2) ^ ((eL & 7) << 4);
                Ah[mr] = *(const short8*)((const char*)AhL + byt);
                Al[mr] = *(const short8*)((const char*)AlL + byt);
            }
            #pragma unroll
            for (int mr = 0; mr < 4; ++mr) {
                accM[mr] = __builtin_amdgcn_mfma_f32_16x16x32_bf16(Ah[mr], Bh[0][ks], accM[mr], 0, 0, 0);
                accE[mr] = __builtin_amdgcn_mfma_f32_16x16x32_bf16(Ah[mr], Bh[1][ks], accE[mr], 0, 0, 0);
                accM[mr] = __builtin_amdgcn_mfma_f32_16x16x32_bf16(Ah[mr], Bl[0][ks], accM[mr], 0, 0, 0);
                accE[mr] = __builtin_amdgcn_mfma_f32_16x16x32_bf16(Ah[mr], Bl[1][ks], accE[mr], 0, 0, 0);
                accM[mr] = __builtin_amdgcn_mfma_f32_16x16x32_bf16(Al[mr], Bh[0][ks], accM[mr], 0, 0, 0);
                accE[mr] = __builtin_amdgcn_mfma_f32_16x16x32_bf16(Al[mr], Bh[1][ks], accE[mr], 0, 0, 0);
            }
        }
        if (TILE < t1) {
            #pragma unroll
            for (int mr = 0; mr < 4; ++mr) {
                #pragma unroll
                for (int r = 0; r < 4; ++r) {
                    int eL  = mr * 16 + lhi * 4 + r;   // C row -> edge in tile
                    int e64 = TILE * 64 + eL;
                    if (e64 < E) {
                        int se = sE[eL], de = dE[eL];
                        float qv = q  [(size_t)se * DD + chan];
                        float kv = kk_[(size_t)de * DD + chan];
                        float vv = v  [(size_t)se * DD + chan];
                        float mval = accM[mr][r] + bmc;
                        float eval_ = accE[mr][r] + bec;
                        float sc = fmaf(mval, qv - kv, eval_);
                        float w  = __expf(sc);
                        unsafeAtomicAdd(&den[(size_t)de * DD + chan], w);
                        unsafeAtomicAdd(&num[(size_t)de * DD + chan], vv * w);
                    }
                }
            }
        }
    };

    stage(bufA, sA, dA, t0);
    for (int tt = t0; tt < t1; tt += 2) {
        __syncthreads();                    // prev tile's LDS fully consumed
        ldswrite(bufA, sA, dA, tt);
        __syncthreads();
        stage(bufB, sB, dB, tt + 1);        // T14: issue next loads pre-compute
        compute(tt);
        __syncthreads();
        ldswrite(bufB, sB, dB, tt + 1);
        __syncthreads();
        stage(bufA, sA, dA, tt + 2);
        compute(tt + 1);
    }
}

// ---------------------------------------------------------------------------
// Generic 128->128 linear kernel with fused epilogues (fp32 GEMV, 8-row tile).
// MODE 0: y = x @ W + b                        (q, k, v)
// MODE 1: x = num/den + node_feats ; y = LN_f(mish(x @ W + b))
// MODE 2: y = LN_ln(x @ W + b)                 (final output)
// ---------------------------------------------------------------------------
template <int MODE>
__global__ __launch_bounds__(512)
void lin_kernel(const float* __restrict__ xin,
                const float* __restrict__ numv, const float* __restrict__ denv,
                const float* __restrict__ W, const float* __restrict__ bias,
                const float* __restrict__ gamma, const float* __restrict__ beta,
                float* __restrict__ y, int M)
{
    extern __shared__ float lds[];
    __shared__ float red[4][2][8][2];
    float* wl = lds;                // [128][128]
    float* xt = lds + DD * DD;      // [4][128][8]

    const int t = threadIdx.x;
    const int c = t & 127;
    const int g = t >> 7;

    for (int idx = t; idx < DD * DD; idx += 512) wl[idx] = W[idx];
    const float bc = bias[c];
    float gm = 0.f, bt = 0.f;
    if (MODE != 0) { gm = gamma[c]; bt = beta[c]; }
    float* xg = xt + g * (DD * 8);

    const int RPP = 32;
    const int chunks = (M + RPP - 1) / RPP;
    const int npass = (chunks + gridDim.x - 1) / gridDim.x;

    for (int p = 0; p < npass; ++p) {
        const int rb = (p * gridDim.x + blockIdx.x) * RPP + g * 8;

        __syncthreads();
        #pragma unroll
        for (int j = 0; j < 8; ++j) {
            int r = rb + j;
            float xv = 0.f;
            if (r < M) {
                size_t o = (size_t)r * DD + c;
                if (MODE == 1) {
                    float dv = denv[o];
                    float nv = numv[o];
                    xv = xin[o] + ((dv > 0.f) ? nv / dv : 0.f);
                } else {
                    xv = xin[o];
                }
            }
            xg[c * 8 + j] = xv;
        }
        __syncthreads();

        float acc[8];
        #pragma unroll
        for (int j = 0; j < 8; ++j) acc[j] = bc;
        #pragma unroll 2
        for (int i = 0; i < DD; ++i) {
            float wv = wl[i * DD + c];
            #pragma unroll
            for (int j = 0; j < 8; ++j)
                acc[j] = fmaf(xg[i * 8 + j], wv, acc[j]);
        }

        if (MODE == 0) {
            #pragma unroll
            for (int j = 0; j < 8; ++j) {
                int r = rb + j;
                if (r < M) y[(size_t)r * DD + c] = acc[j];
            }
        } else {
            float mv[8];
            #pragma unroll
            for (int j = 0; j < 8; ++j) {
                float a = acc[j];
                if (MODE == 1) {
                    float sp = fmaxf(a, 0.f) + log1pf(__expf(-fabsf(a)));
                    mv[j] = a * tanhf(sp);
                } else {
                    mv[j] = a;
                }
            }
            const int lane = t & 63;
            const int wv2 = (t >> 6) & 1;
            #pragma unroll
            for (int j = 0; j < 8; ++j) {
                float s1 = mv[j];
                float s2 = mv[j] * mv[j];
                #pragma unroll
                for (int off = 32; off > 0; off >>= 1) {
                    s1 += __shfl_xor(s1, off);
                    s2 += __shfl_xor(s2, off);
                }
                if (lane == 0) {
                    red[g][wv2][j][0] = s1;
                    red[g][wv2][j][1] = s2;
                }
            }
            __syncthreads();
            #pragma unroll
            for (int j = 0; j < 8; ++j) {
                float S1 = red[g][0][j][0] + red[g][1][j][0];
                float S2 = red[g][0][j][1] + red[g][1][j][1];
                float mu  = S1 * (1.f / 128.f);
                float var = S2 * (1.f / 128.f) - mu * mu;
                float rs  = rsqrtf(var + 1e-5f);
                float o = (mv[j] - mu) * rs * gm + bt;
                int r = rb + j;
                if (r < M) y[(size_t)r * DD + c] = o;
            }
        }
    }
}

// ---------------------------------------------------------------------------
extern "C" void kernel_launch(void* const* d_in, const int* in_sizes, int n_in,
                              void* d_out, int out_size, void* d_ws, size_t ws_size,
                              hipStream_t stream)
{
    const float* nf  = (const float*)d_in[0];
    const float* ef  = (const float*)d_in[1];
    const int*   src = (const int*)d_in[2];
    const int*   dst = (const int*)d_in[3];
    const float* Wq  = (const float*)d_in[4];  const float* bq  = (const float*)d_in[5];
    const float* Wk  = (const float*)d_in[6];  const float* bk  = (const float*)d_in[7];
    const float* Wv  = (const float*)d_in[8];  const float* bv  = (const float*)d_in[9];
    const float* We  = (const float*)d_in[10]; const float* be  = (const float*)d_in[11];
    const float* Wm  = (const float*)d_in[12]; const float* bm  = (const float*)d_in[13];
    const float* Wf1 = (const float*)d_in[14]; const float* bf1 = (const float*)d_in[15];
    const float* g_f = (const float*)d_in[16]; const float* b_f = (const float*)d_in[17];
    const float* Wf2 = (const float*)d_in[18]; const float* bf2 = (const float*)d_in[19];
    const float* g_ln = (const float*)d_in[20]; const float* b_ln = (const float*)d_in[21];

    const int N = in_sizes[0] / DD;
    const int E = in_sizes[2];

    float* out   = (float*)d_out;
    float* out_h = out;                        // [N,128]
    float* out_e = out + (size_t)N * DD;       // [E,128] passthrough

    float* ws   = (float*)d_ws;
    float* q    = ws;
    float* k    = q    + (size_t)N * DD;
    float* v    = k    + (size_t)N * DD;
    float* numb = v    + (size_t)N * DD;
    float* denb = numb + (size_t)N * DD;
    float* hmid = q;  // reuse q (dead after edge kernel)

    // num/den are atomically accumulated -> must start at 0 (ws is poisoned)
    hipMemsetAsync(numb, 0, (size_t)N * DD * 2 * sizeof(float), stream);

    const size_t lds_lin = (size_t)(DD * DD + 4 * DD * 8) * sizeof(float);  // 80 KB
    hipFuncSetAttribute(reinterpret_cast<const void*>(lin_kernel<0>),
                        hipFuncAttributeMaxDynamicSharedMemorySize, (int)lds_lin);
    hipFuncSetAttribute(reinterpret_cast<const void*>(lin_kernel<1>),
                        hipFuncAttributeMaxDynamicSharedMemorySize, (int)lds_lin);
    hipFuncSetAttribute(reinterpret_cast<const void*>(lin_kernel<2>),
                        hipFuncAttributeMaxDynamicSharedMemorySize, (int)lds_lin);

    dim3 blk(512);

    // q, k, v projections
    lin_kernel<0><<<512, blk, lds_lin, stream>>>(nf, nullptr, nullptr, Wq, bq, nullptr, nullptr, q, N);
    lin_kernel<0><<<512, blk, lds_lin, stream>>>(nf, nullptr, nullptr, Wk, bk, nullptr, nullptr, k, N);
    lin_kernel<0><<<512, blk, lds_lin, stream>>>(nf, nullptr, nullptr, Wv, bv, nullptr, nullptr, v, N);

    // fused MFMA edge pipeline (scores + softmax-accumulate + aggregate + ef copy)
    edge_mfma<<<256, blk, 0, stream>>>(ef, Wm, bm, We, be, q, k, v,
                                       src, dst, numb, denb, out_e, E);

    // h = num/den + nf -> FFN1 + mish + LN_f
    lin_kernel<1><<<512, blk, lds_lin, stream>>>(nf, numb, denb, Wf1, bf1, g_f, b_f, hmid, N);
    // FFN2 + LN_ln -> output
    lin_kernel<2><<<512, blk, lds_lin, stream>>>(hmid, nullptr, nullptr, Wf2, bf2, g_ln, b_ln, out_h, N);
}

// Round 4
// 1510.481 us; speedup vs baseline: 1.3073x; 1.3073x over previous
//
#include <hip/hip_runtime.h>
#include <cstddef>
#include <cstdint>

#define DD 128

typedef __attribute__((ext_vector_type(8))) short short8;
typedef __attribute__((ext_vector_type(4))) float f32x4;

__device__ __forceinline__ unsigned short bf16_rne(float x) {
    union { float f; unsigned u; } a; a.f = x;
    unsigned u = a.u;
    u += 0x7FFFu + ((u >> 16) & 1u);
    return (unsigned short)(u >> 16);
}
__device__ __forceinline__ float bf16_f32(unsigned short h) {
    union { float f; unsigned u; } a; a.u = ((unsigned)h) << 16;
    return a.f;
}
__device__ __forceinline__ void split2(float x, unsigned short& h, unsigned short& l) {
    h = bf16_rne(x);
    l = bf16_rne(x - bf16_f32(h));
}

// ---------------------------------------------------------------------------
// Edge kernel, MFMA split-bf16. Math verified correct in Round 2. Deltas vs
// the measured Round-2 config (these are what THIS bench measures):
//   grid 256->512 (2 blocks/CU), launch_bounds(512,4), nontemporal ef/ef_out.
// MFMA 16x16x32_bf16: A[row=l&15][k=8*(l>>4)+j]; B[k][col=l&15];
// C[row=4*(l>>4)+reg][col=l&15]  (correctness-verified in round 2).
// ---------------------------------------------------------------------------
__global__ __launch_bounds__(512, 4)
void edge_mfma(const float* __restrict__ ef,
               const float* __restrict__ Wm, const float* __restrict__ bm_,
               const float* __restrict__ We, const float* __restrict__ be_,
               const float* __restrict__ q, const float* __restrict__ kk_,
               const float* __restrict__ v,
               const int* __restrict__ src, const int* __restrict__ dst,
               float* __restrict__ num, float* __restrict__ den,
               float* __restrict__ ef_out, int E)
{
    __shared__ unsigned short AhL[64 * DD];   // hi bf16, swizzled [64][128]
    __shared__ unsigned short AlL[64 * DD];   // lo bf16
    __shared__ int sE[64], dE[64];

    const int t    = threadIdx.x;
    const int lane = t & 63;
    const int wid  = t >> 6;
    const int l15  = lane & 15;
    const int lhi  = lane >> 4;
    const int chan = wid * 16 + l15;

    const float bmc = bm_[chan];
    const float bec = be_[chan];

    short8 Bh[2][4], Bl[2][4];
    #pragma unroll
    for (int mat = 0; mat < 2; ++mat) {
        const float* Wp = mat ? We : Wm;
        #pragma unroll
        for (int ks = 0; ks < 4; ++ks) {
            short8 h8, l8;
            #pragma unroll
            for (int j = 0; j < 8; ++j) {
                float w = Wp[(ks * 32 + lhi * 8 + j) * DD + chan];
                unsigned short h, l; split2(w, h, l);
                h8[j] = (short)h; l8[j] = (short)l;
            }
            Bh[mat][ks] = h8; Bl[mat][ks] = l8;
        }
    }

    const int ntiles = (E + 63) >> 6;
    const int per = (ntiles + gridDim.x - 1) / gridDim.x;
    const int t0 = blockIdx.x * per;
    const int t1 = min(ntiles, t0 + per);
    if (t0 >= t1) return;

    f32x4 bufA[4], bufB[4];
    int sA = 0, dA = 0, sB = 0, dB = 0;

    auto stage = [&](f32x4 (&RF)[4], int& RS, int& RD, int TILE) {
        const bool act = TILE < t1;
        const size_t base = (size_t)TILE * (64 * DD);
        #pragma unroll
        for (int p = 0; p < 4; ++p) {
            size_t idx = base + (size_t)(p * 512 + t) * 4;
            if (act && idx < (size_t)E * DD)
                RF[p] = __builtin_nontemporal_load((const f32x4*)(ef + idx));
            else
                RF[p] = (f32x4){0.f, 0.f, 0.f, 0.f};
        }
        if (t < 64) {
            int e64 = TILE * 64 + t;
            bool ok = act && (e64 < E);
            RS = ok ? src[e64] : 0;
            RD = ok ? dst[e64] : 0;
        }
    };

    auto ldswrite = [&](f32x4 (&RF)[4], int RS, int RD, int TILE) {
        const bool act = TILE < t1;
        if (t < 64) { sE[t] = RS; dE[t] = RD; }
        #pragma unroll
        for (int p = 0; p < 4; ++p) {
            int f  = (p * 512 + t) * 4;
            int eL = f >> 7;
            int byt = (eL * 256 + (f & 127) * 2) ^ ((eL & 7) << 4);  // T2 swizzle
            ushort4 hi4, lo4;
            split2(RF[p][0], hi4.x, lo4.x);
            split2(RF[p][1], hi4.y, lo4.y);
            split2(RF[p][2], hi4.z, lo4.z);
            split2(RF[p][3], hi4.w, lo4.w);
            *(ushort4*)((char*)AhL + byt) = hi4;
            *(ushort4*)((char*)AlL + byt) = lo4;
            size_t gidx = (size_t)TILE * (64 * DD) + f;
            if (act && gidx < (size_t)E * DD)
                __builtin_nontemporal_store(RF[p], (f32x4*)(ef_out + gidx));
        }
    };

    auto compute = [&](int TILE) {
        f32x4 accM[4], accE[4];
        #pragma unroll
        for (int mr = 0; mr < 4; ++mr) {
            accM[mr] = (f32x4){0.f, 0.f, 0.f, 0.f};
            accE[mr] = (f32x4){0.f, 0.f, 0.f, 0.f};
        }
        #pragma unroll
        for (int ks = 0; ks < 4; ++ks) {
            short8 Ah[4], Al[4];
            #pragma unroll
            for (int mr = 0; mr < 4; ++mr) {
                int eL  = mr * 16 + l15;
                int byt = (eL * 256 + (ks * 32 + lhi * 8) * 2) ^ ((eL & 7) << 4);
                Ah[mr] = *(const short8*)((const char*)AhL + byt);
                Al[mr] = *(const short8*)((const char*)AlL + byt);
            }
            #pragma unroll
            for (int mr = 0; mr < 4; ++mr) {
                accM[mr] = __builtin_amdgcn_mfma_f32_16x16x32_bf16(Ah[mr], Bh[0][ks], accM[mr], 0, 0, 0);
                accE[mr] = __builtin_amdgcn_mfma_f32_16x16x32_bf16(Ah[mr], Bh[1][ks], accE[mr], 0, 0, 0);
                accM[mr] = __builtin_amdgcn_mfma_f32_16x16x32_bf16(Ah[mr], Bl[0][ks], accM[mr], 0, 0, 0);
                accE[mr] = __builtin_amdgcn_mfma_f32_16x16x32_bf16(Ah[mr], Bl[1][ks], accE[mr], 0, 0, 0);
                accM[mr] = __builtin_amdgcn_mfma_f32_16x16x32_bf16(Al[mr], Bh[0][ks], accM[mr], 0, 0, 0);
                accE[mr] = __builtin_amdgcn_mfma_f32_16x16x32_bf16(Al[mr], Bh[1][ks], accE[mr], 0, 0, 0);
            }
        }
        if (TILE < t1) {
            #pragma unroll
            for (int mr = 0; mr < 4; ++mr) {
                #pragma unroll
                for (int r = 0; r < 4; ++r) {
                    int eL  = mr * 16 + lhi * 4 + r;
                    int e64 = TILE * 64 + eL;
                    if (e64 < E) {
                        int se = sE[eL], de = dE[eL];
                        float qv = q  [(size_t)se * DD + chan];
                        float kv = kk_[(size_t)de * DD + chan];
                        float vv = v  [(size_t)se * DD + chan];
                        float mval  = accM[mr][r] + bmc;
                        float eval_ = accE[mr][r] + bec;
                        float sc = fmaf(mval, qv - kv, eval_);
                        float w  = __expf(sc);
                        unsafeAtomicAdd(&den[(size_t)de * DD + chan], w);
                        unsafeAtomicAdd(&num[(size_t)de * DD + chan], vv * w);
                    }
                }
            }
        }
    };

    stage(bufA, sA, dA, t0);
    for (int tt = t0; tt < t1; tt += 2) {
        __syncthreads();
        ldswrite(bufA, sA, dA, tt);
        __syncthreads();
        stage(bufB, sB, dB, tt + 1);
        compute(tt);
        __syncthreads();
        ldswrite(bufB, sB, dB, tt + 1);
        __syncthreads();
        stage(bufA, sA, dA, tt + 2);
        compute(tt + 1);
    }
}

// ---------------------------------------------------------------------------
// MFMA split-bf16 linear kernel, one 64-row tile per block.
// MODE 0: y = x @ W + b
// MODE 1: x = nf + num/den ; y = LN_f(mish(x @ W + b))
// MODE 2: y = LN_ln(x @ W + b)
// LN epilogue transposes through an XOR-swizzled f32 LDS buffer that ALIASES
// the (dead) A-tile staging LDS -> static LDS stays 32 KB.
// ---------------------------------------------------------------------------
template <int MODE>
__global__ __launch_bounds__(512, 4)
void lin_mfma(const float* __restrict__ xin,
              const float* __restrict__ numv, const float* __restrict__ denv,
              const float* __restrict__ W, const float* __restrict__ bias,
              const float* __restrict__ gamma, const float* __restrict__ beta,
              float* __restrict__ y, int M)
{
    __shared__ unsigned short AL[2][64 * DD];   // [hi|lo], 32 KB total
    float* rbuf = (float*)AL;                   // aliases AL after MFMA

    const int t    = threadIdx.x;
    const int lane = t & 63;
    const int wid  = t >> 6;
    const int l15  = lane & 15;
    const int lhi  = lane >> 4;
    const int chan = wid * 16 + l15;

    const float bc = bias[chan];

    short8 Bh[4], Bl[4];
    #pragma unroll
    for (int ks = 0; ks < 4; ++ks) {
        short8 h8, l8;
        #pragma unroll
        for (int j = 0; j < 8; ++j) {
            float w = W[(ks * 32 + lhi * 8 + j) * DD + chan];
            unsigned short h, l; split2(w, h, l);
            h8[j] = (short)h; l8[j] = (short)l;
        }
        Bh[ks] = h8; Bl[ks] = l8;
    }

    const int tile = blockIdx.x;
    const size_t base = (size_t)tile * (64 * DD);

    // ---- stage x tile (hi/lo bf16, T2-swizzled) ----
    #pragma unroll
    for (int p = 0; p < 4; ++p) {
        int f = (p * 512 + t) * 4;
        size_t idx = base + (size_t)f;
        f32x4 xv = (f32x4){0.f, 0.f, 0.f, 0.f};
        if ((int)(idx >> 7) < M) {
            if (MODE == 1) {
                f32x4 x4 = *(const f32x4*)(xin + idx);
                f32x4 n4 = *(const f32x4*)(numv + idx);
                f32x4 d4 = *(const f32x4*)(denv + idx);
                #pragma unroll
                for (int c2 = 0; c2 < 4; ++c2)
                    xv[c2] = x4[c2] + ((d4[c2] > 0.f) ? n4[c2] / d4[c2] : 0.f);
            } else {
                xv = *(const f32x4*)(xin + idx);
            }
        }
        int row = f >> 7;
        int byt = (row * 256 + (f & 127) * 2) ^ ((row & 7) << 4);
        ushort4 hi4, lo4;
        split2(xv[0], hi4.x, lo4.x);
        split2(xv[1], hi4.y, lo4.y);
        split2(xv[2], hi4.z, lo4.z);
        split2(xv[3], hi4.w, lo4.w);
        *(ushort4*)((char*)AL[0] + byt) = hi4;
        *(ushort4*)((char*)AL[1] + byt) = lo4;
    }
    __syncthreads();

    // ---- 3-term split-bf16 MFMA ----
    f32x4 acc[4];
    #pragma unroll
    for (int mr = 0; mr < 4; ++mr) acc[mr] = (f32x4){0.f, 0.f, 0.f, 0.f};
    #pragma unroll
    for (int ks = 0; ks < 4; ++ks) {
        short8 Ah[4], Al8[4];
        #pragma unroll
        for (int mr = 0; mr < 4; ++mr) {
            int r = mr * 16 + l15;
            int byt = (r * 256 + (ks * 32 + lhi * 8) * 2) ^ ((r & 7) << 4);
            Ah[mr]  = *(const short8*)((const char*)AL[0] + byt);
            Al8[mr] = *(const short8*)((const char*)AL[1] + byt);
        }
        #pragma unroll
        for (int mr = 0; mr < 4; ++mr) {
            acc[mr] = __builtin_amdgcn_mfma_f32_16x16x32_bf16(Ah[mr],  Bh[ks], acc[mr], 0, 0, 0);
            acc[mr] = __builtin_amdgcn_mfma_f32_16x16x32_bf16(Al8[mr], Bh[ks], acc[mr], 0, 0, 0);
            acc[mr] = __builtin_amdgcn_mfma_f32_16x16x32_bf16(Ah[mr],  Bl[ks], acc[mr], 0, 0, 0);
        }
    }

    if (MODE == 0) {
        #pragma unroll
        for (int mr = 0; mr < 4; ++mr) {
            #pragma unroll
            for (int r = 0; r < 4; ++r) {
                int row = tile * 64 + mr * 16 + lhi * 4 + r;
                if (row < M) y[(size_t)row * DD + chan] = acc[mr][r] + bc;
            }
        }
    } else {
        __syncthreads();   // all A-frag LDS reads done before aliasing as rbuf
        #pragma unroll
        for (int mr = 0; mr < 4; ++mr) {
            #pragma unroll
            for (int r = 0; r < 4; ++r) {
                int rl = mr * 16 + lhi * 4 + r;
                float a = acc[mr][r] + bc;
                if (MODE == 1) {
                    float sp = fmaxf(a, 0.f) + log1pf(__expf(-fabsf(a)));
                    a = a * tanhf(sp);
                }
                int byt = (rl * 512 + chan * 4) ^ ((rl & 7) << 4);
                *(float*)((char*)rbuf + byt) = a;
            }
        }
        __syncthreads();
        // per-row LayerNorm: 8 threads per row, 16 channels each
        const int row  = t >> 3;
        const int part = t & 7;
        f32x4 vv[4];
        #pragma unroll
        for (int u = 0; u < 4; ++u) {
            int byt = (row * 512 + (part * 16 + u * 4) * 4) ^ ((row & 7) << 4);
            vv[u] = *(const f32x4*)((const char*)rbuf + byt);
        }
        float s1 = 0.f, s2 = 0.f;
        #pragma unroll
        for (int u = 0; u < 4; ++u)
            #pragma unroll
            for (int c2 = 0; c2 < 4; ++c2) {
                s1 += vv[u][c2];
                s2 += vv[u][c2] * vv[u][c2];
            }
        #pragma unroll
        for (int off = 1; off < 8; off <<= 1) {
            s1 += __shfl_xor(s1, off);
            s2 += __shfl_xor(s2, off);
        }
        float mu  = s1 * (1.f / 128.f);
        float var = s2 * (1.f / 128.f) - mu * mu;
        float rs  = rsqrtf(var + 1e-5f);
        int grow = tile * 64 + row;
        if (grow < M) {
            #pragma unroll
            for (int u = 0; u < 4; ++u) {
                f32x4 g4 = *(const f32x4*)(gamma + part * 16 + u * 4);
                f32x4 b4 = *(const f32x4*)(beta  + part * 16 + u * 4);
                f32x4 o;
                #pragma unroll
                for (int c2 = 0; c2 < 4; ++c2)
                    o[c2] = (vv[u][c2] - mu) * rs * g4[c2] + b4[c2];
                *(f32x4*)(y + (size_t)grow * DD + part * 16 + u * 4) = o;
            }
        }
    }
}

// ---------------------------------------------------------------------------
extern "C" void kernel_launch(void* const* d_in, const int* in_sizes, int n_in,
                              void* d_out, int out_size, void* d_ws, size_t ws_size,
                              hipStream_t stream)
{
    const float* nf  = (const float*)d_in[0];
    const float* ef  = (const float*)d_in[1];
    const int*   src = (const int*)d_in[2];
    const int*   dst = (const int*)d_in[3];
    const float* Wq  = (const float*)d_in[4];  const float* bq  = (const float*)d_in[5];
    const float* Wk  = (const float*)d_in[6];  const float* bk  = (const float*)d_in[7];
    const float* Wv  = (const float*)d_in[8];  const float* bv  = (const float*)d_in[9];
    const float* We  = (const float*)d_in[10]; const float* be  = (const float*)d_in[11];
    const float* Wm  = (const float*)d_in[12]; const float* bm  = (const float*)d_in[13];
    const float* Wf1 = (const float*)d_in[14]; const float* bf1 = (const float*)d_in[15];
    const float* g_f = (const float*)d_in[16]; const float* b_f = (const float*)d_in[17];
    const float* Wf2 = (const float*)d_in[18]; const float* bf2 = (const float*)d_in[19];
    const float* g_ln = (const float*)d_in[20]; const float* b_ln = (const float*)d_in[21];

    const int N = in_sizes[0] / DD;
    const int E = in_sizes[2];

    float* out   = (float*)d_out;
    float* out_h = out;                        // [N,128]
    float* out_e = out + (size_t)N * DD;       // [E,128] passthrough

    float* ws   = (float*)d_ws;
    float* q    = ws;
    float* k    = q    + (size_t)N * DD;
    float* v    = k    + (size_t)N * DD;
    float* numb = v    + (size_t)N * DD;
    float* denb = numb + (size_t)N * DD;
    float* hmid = q;  // reuse q (dead after edge kernel)

    // num/den are atomically accumulated -> must start at 0 (ws is poisoned)
    hipMemsetAsync(numb, 0, (size_t)N * DD * 2 * sizeof(float), stream);

    dim3 blk(512);
    const int ntiles_n = (N + 63) / 64;

    // q, k, v projections (MFMA)
    lin_mfma<0><<<ntiles_n, blk, 0, stream>>>(nf, nullptr, nullptr, Wq, bq, nullptr, nullptr, q, N);
    lin_mfma<0><<<ntiles_n, blk, 0, stream>>>(nf, nullptr, nullptr, Wk, bk, nullptr, nullptr, k, N);
    lin_mfma<0><<<ntiles_n, blk, 0, stream>>>(nf, nullptr, nullptr, Wv, bv, nullptr, nullptr, v, N);

    // fused MFMA edge pipeline (scores + softmax-accumulate + aggregate + ef copy)
    edge_mfma<<<512, blk, 0, stream>>>(ef, Wm, bm, We, be, q, k, v,
                                       src, dst, numb, denb, out_e, E);

    // h = num/den + nf -> FFN1 + mish + LN_f
    lin_mfma<1><<<ntiles_n, blk, 0, stream>>>(nf, numb, denb, Wf1, bf1, g_f, b_f, hmid, N);
    // FFN2 + LN_ln -> output
    lin_mfma<2><<<ntiles_n, blk, 0, stream>>>(hmid, nullptr, nullptr, Wf2, bf2, g_ln, b_ln, out_h, N);
}